// Round 4
// baseline (646.011 us; speedup 1.0000x reference)
//
#include <hip/hip_runtime.h>
#include <hip/hip_bf16.h>
#include <cmath>

#define T_STEPS 16
#define BATCH   512
#define N_IN    3072
#define S1      256
#define S2      256
#define S3      128
#define NEXP    8
#define M_ROWS  (T_STEPS * BATCH)   // 8192
#define M_HALF  (M_ROWS / 2)        // 4096
#define NT1     256                 // stage-1 B fragment tiles in n (8192/32)

typedef int v4i  __attribute__((ext_vector_type(4)));
typedef int v16i __attribute__((ext_vector_type(16)));
typedef unsigned long long u64;
typedef unsigned int uint32;

// ---------------------------------------------------------------------------
// async global->LDS 16B (stages 2/3 path)
// ---------------------------------------------------------------------------
__device__ __forceinline__ void gl2lds16(const char* g, char* l) {
    __builtin_amdgcn_global_load_lds(
        (const __attribute__((address_space(1))) void*)g,
        (__attribute__((address_space(3))) void*)l, 16, 0, 0);
}

// ---------------------------------------------------------------------------
// pack binary fp32 x -> 1 bit/elem via wave ballot. bits[m][K/64] (u64).
// ---------------------------------------------------------------------------
__global__ __launch_bounds__(256) void pack_x_bits(
    const float* __restrict__ x, u64* __restrict__ bits)
{
    int gid = blockIdx.x * 256 + threadIdx.x;
    float v = x[gid];
    u64 m = __ballot(v >= 0.5f);
    if ((threadIdx.x & 63) == 0) bits[gid >> 6] = m;
}

// ---------------------------------------------------------------------------
// Stage-1 weight digitize -> MFMA fragment-tile layout.
// w -> round(w*2^32) = sum_l d_l*256^l. B-row gr = (e*S1+n)*4 + limb.
// Fragment tiles: Bf[kb][nt][lane][16], kb=k/32, nt=gr/32,
// lane = (gr&31) + 32*((k>>4)&1), byte = k&15.
// ---------------------------------------------------------------------------
__global__ __launch_bounds__(256) void digitize_w_frag(
    const float* __restrict__ W, char* __restrict__ Bf)
{
    long long t = (long long)blockIdx.x * 256 + threadIdx.x;  // one per weight
    long long row = t / N_IN;          // e*S1 + n
    int k = (int)(t - row * N_IN);
    double w = (double)W[t];
    long long q = llrint(w * 4294967296.0);
    int kb = k >> 5, qd = (k >> 4) & 1, kbyte = k & 15;
    #pragma unroll
    for (int l = 0; l < 4; ++l) {
        int d = (int)((q + 128) & 255) - 128;
        q = (q - d) >> 8;
        long long gr = row * 4 + l;
        long long nt = gr >> 5;
        int r = (int)(gr & 31);
        Bf[(((long long)kb * NT1 + nt) * 64 + (r + 32 * qd)) * 16 + kbyte] = (char)d;
    }
}

// ---------------------------------------------------------------------------
// Row-major digitize for stages 2/3 (gemm_i8 path).
// ---------------------------------------------------------------------------
__global__ __launch_bounds__(256) void digitize_w(
    const float* __restrict__ W, char* __restrict__ Bd, int K, long long total4)
{
    long long t = (long long)blockIdx.x * 256 + threadIdx.x;
    if (t >= total4) return;
    const int kq = K >> 2;
    long long row = t / kq;
    int kc = (int)(t - row * kq);
    float4 w = ((const float4*)W)[t];
    long long q[4];
    q[0] = llrint((double)w.x * 4294967296.0);
    q[1] = llrint((double)w.y * 4294967296.0);
    q[2] = llrint((double)w.z * 4294967296.0);
    q[3] = llrint((double)w.w * 4294967296.0);
    char* base = Bd + row * 4 * (long long)K + kc * 4;
    #pragma unroll
    for (int l = 0; l < 4; ++l) {
        char4 d;
        int d0 = (int)((q[0] + 128) & 255) - 128; q[0] = (q[0] - d0) >> 8;
        int d1 = (int)((q[1] + 128) & 255) - 128; q[1] = (q[1] - d1) >> 8;
        int d2 = (int)((q[2] + 128) & 255) - 128; q[2] = (q[2] - d2) >> 8;
        int d3 = (int)((q[3] + 128) & 255) - 128; q[3] = (q[3] - d3) >> 8;
        d.x = (char)d0; d.y = (char)d1; d.z = (char)d2; d.w = (char)d3;
        *(char4*)(base + (long long)l * K) = d;
    }
}

// ---------------------------------------------------------------------------
// Stage-1 GEMM: barrier-free, software-pipelined.
// A: bit-packed (M_HALF x K/64 u64). B: fragment tiles (see digitize_w_frag).
// Block 256 = 4 waves stacked in m (wave strip 64 rows); wave tile 64 x 128
// B-rows (2x4 of mfma_i32_32x32x32_i8). B frags global->VGPR, prefetched
// 1 iter. A unpacked per-wave into private LDS (no __syncthreads anywhere).
// Grid: 1-D 1024; id%8 = XCD -> n-slabs grouped per XCD (B L2-resident).
// H layout: [e][nblk=8][m][32] fp64.
// ---------------------------------------------------------------------------
__global__ __launch_bounds__(256, 2) void gemm_s1(
    const u64* __restrict__ Abits, const char* __restrict__ Bf,
    double* __restrict__ H)
{
    constexpr int K = N_IN, KI = K / 64;     // 48 iters
    // [wave][buf][kwin][row][16B] : 32 KB
    __shared__ __align__(16) char Al[4][2][4][64][16];

    const int tid  = threadIdx.x;
    const int lane = tid & 63;
    const int w    = tid >> 6;
    const int col  = lane & 31;
    const int qd   = lane >> 5;

    // swizzled 1-D grid -> (m_blk, n_blk)
    const int id    = blockIdx.x;
    const int m_blk = (id >> 3) & 15;
    const int n_blk = (id & 7) + 8 * (id >> 7);

    const int m0  = m_blk * 256 + w * 64;    // wave's m strip
    const int nb0 = n_blk * 4;               // 4 n-tiles (128 B-rows)

    const u64* Ab = Abits + (size_t)(m0 + lane) * KI;
    char* myA = &Al[w][0][0][0][0];          // wave-private 8 KB (2 bufs)

    v16i acc[2][4];
    #pragma unroll
    for (int i = 0; i < 2; ++i)
        #pragma unroll
        for (int j = 0; j < 4; ++j)
            #pragma unroll
            for (int r = 0; r < 16; ++r) acc[i][j][r] = 0;

    // unpack 64 bits -> 64 i8 (0/1) -> 4x ds_write_b128 into buf p
    auto unpack_store = [&](u64 bits, int p) {
        #pragma unroll
        for (int kw = 0; kw < 4; ++kw) {
            v4i d;
            #pragma unroll
            for (int c = 0; c < 4; ++c) {
                uint32 nib = (uint32)(bits >> (16 * kw + 4 * c)) & 0xFu;
                d[c] = (int)((nib * 0x00204081u) & 0x01010101u);
            }
            *(v4i*)(myA + ((p * 4 + kw) * 64 + lane) * 16) = d;
        }
    };
    auto loadB = [&](int kb, int nt) -> v4i {
        return *(const v4i*)(Bf + (((size_t)kb * NT1 + nt) * 64 + lane) * 16);
    };

    // prologue: iter 0 A-tile unpacked; iter-1 bits and iter-0 B in flight
    u64 bits_b;                // bits for iter it+1 (to unpack this iter)
    unpack_store(Ab[0], 0);
    bits_b = Ab[KI > 1 ? 1 : 0];
    v4i bc[8];
    #pragma unroll
    for (int ks = 0; ks < 2; ++ks)
        #pragma unroll
        for (int j = 0; j < 4; ++j) bc[ks * 4 + j] = loadB(ks, nb0 + j);

    for (int it = 0; it < KI; ++it) {
        const int itn  = (it + 1 < KI) ? it + 1 : KI - 1;
        const int itn2 = (it + 2 < KI) ? it + 2 : KI - 1;

        // prefetch B(it+1) and bits(it+2)
        v4i bn[8];
        #pragma unroll
        for (int ks = 0; ks < 2; ++ks)
            #pragma unroll
            for (int j = 0; j < 4; ++j)
                bn[ks * 4 + j] = loadB(itn * 2 + ks, nb0 + j);
        u64 bits_c = Ab[itn2];

        // unpack A-tile for it+1 into the other buffer (no reader conflict)
        unpack_store(bits_b, (it + 1) & 1);

        // compute iter it: A frags from buf (it&1), B from regs
        const int p = it & 1;
        #pragma unroll
        for (int ks = 0; ks < 2; ++ks) {
            v4i af0 = *(const v4i*)(myA + ((p * 4 + ks * 2 + qd) * 64 + col) * 16);
            v4i af1 = *(const v4i*)(myA + ((p * 4 + ks * 2 + qd) * 64 + 32 + col) * 16);
            #pragma unroll
            for (int j = 0; j < 4; ++j) {
                acc[0][j] = __builtin_amdgcn_mfma_i32_32x32x32_i8(
                    af0, bc[ks * 4 + j], acc[0][j], 0, 0, 0);
                acc[1][j] = __builtin_amdgcn_mfma_i32_32x32x32_i8(
                    af1, bc[ks * 4 + j], acc[1][j], 0, 0, 0);
            }
        }
        bits_b = bits_c;
        #pragma unroll
        for (int q2 = 0; q2 < 8; ++q2) bc[q2] = bn[q2];
    }

    // epilogue: recombine 4 limbs (adjacent C cols) exactly in double
    const double sbase = 1.0 / 4294967296.0;   // 2^-32
    #pragma unroll
    for (int j = 0; j < 4; ++j) {
        int brow  = n_blk * 128 + j * 32 + col;
        int limb  = brow & 3;
        int nglob = brow >> 2;                 // e*256 + nloc
        int e     = nglob >> 8;
        int nloc  = nglob & 255;
        double lscale = (double)(1 << (8 * limb)) * sbase;
        size_t hb = (((size_t)e * 8 + (nloc >> 5)) * M_HALF) * 32 + (nloc & 31);
        #pragma unroll
        for (int i = 0; i < 2; ++i) {
            #pragma unroll
            for (int reg = 0; reg < 16; ++reg) {
                double d = (double)acc[i][j][reg] * lscale;
                d += __shfl_xor(d, 1);
                d += __shfl_xor(d, 2);
                if ((lane & 3) == 0) {
                    int m = m0 + i * 32 + (reg & 3) + 8 * (reg >> 2) + 4 * qd;
                    H[hb + (size_t)m * 32] = d;
                }
            }
        }
    }
}

// ---------------------------------------------------------------------------
// Stages 2/3 GEMM (R3 path, unchanged semantics).
// ---------------------------------------------------------------------------
template<int K, int S, int SHIFT>
__global__ __launch_bounds__(256) void gemm_i8(
    const char* __restrict__ A, const char* __restrict__ B,
    double* __restrict__ H)
{
    __shared__ __align__(16) char As[128 * 128];
    __shared__ __align__(16) char Bs[128 * 128];

    const int tid  = threadIdx.x;
    const int lane = tid & 63;
    const int wave = tid >> 6;
    const int wm  = (wave & 1) * 64;
    const int wn  = (wave >> 1) * 64;
    const int col = lane & 31;
    const int qd  = lane >> 5;

    const char* Ag = A + (size_t)(blockIdx.x * 128) * K;
    const char* Bg = B + (size_t)(blockIdx.y * 128) * K;

    v16i acc[2][2];
    #pragma unroll
    for (int i = 0; i < 2; ++i)
        #pragma unroll
        for (int j = 0; j < 2; ++j)
            #pragma unroll
            for (int r = 0; r < 16; ++r) acc[i][j][r] = 0;

    for (int k0 = 0; k0 < K; k0 += 128) {
        #pragma unroll
        for (int i = 0; i < 4; ++i) {
            int slot = tid + i * 256;
            int row  = slot >> 3;
            int ch   = (slot & 7) ^ (row & 7);
            gl2lds16(Ag + (size_t)row * K + k0 + ch * 16, As + slot * 16);
            gl2lds16(Bg + (size_t)row * K + k0 + ch * 16, Bs + slot * 16);
        }
        __syncthreads();

        #pragma unroll
        for (int ks = 0; ks < 4; ++ks) {
            v4i af[2], bf[2];
            #pragma unroll
            for (int i = 0; i < 2; ++i) {
                int row = wm + i * 32 + col;
                int ch  = (ks * 2 + qd) ^ (row & 7);
                af[i] = *(const v4i*)(As + row * 128 + ch * 16);
            }
            #pragma unroll
            for (int j = 0; j < 2; ++j) {
                int row = wn + j * 32 + col;
                int ch  = (ks * 2 + qd) ^ (row & 7);
                bf[j] = *(const v4i*)(Bs + row * 128 + ch * 16);
            }
            #pragma unroll
            for (int i = 0; i < 2; ++i)
                #pragma unroll
                for (int j = 0; j < 2; ++j)
                    acc[i][j] = __builtin_amdgcn_mfma_i32_32x32x32_i8(
                        af[i], bf[j], acc[i][j], 0, 0, 0);
        }
        __syncthreads();
    }

    const double sbase = 1.0 / (double)(1ll << SHIFT);
    #pragma unroll
    for (int j = 0; j < 2; ++j) {
        int brow  = blockIdx.y * 128 + wn + j * 32 + col;
        int limb  = brow & 3;
        int nglob = brow >> 2;
        int e     = nglob / S;
        int nloc  = nglob % S;
        double lscale = (double)(1 << (8 * limb)) * sbase;
        size_t hb = (((size_t)e * (S / 32) + (nloc >> 5)) * M_HALF) * 32 + (nloc & 31);
        #pragma unroll
        for (int i = 0; i < 2; ++i) {
            #pragma unroll
            for (int reg = 0; reg < 16; ++reg) {
                double d = (double)acc[i][j][reg] * lscale;
                d += __shfl_xor(d, 1);
                d += __shfl_xor(d, 2);
                if ((lane & 3) == 0) {
                    int m = blockIdx.x * 128 + wm + i * 32
                          + (reg & 3) + 8 * (reg >> 2) + 4 * qd;
                    H[hb + (size_t)m * 32] = d;
                }
            }
        }
    }
}

// ---------------------------------------------------------------------------
// LIF scan over one T-half (8 steps). fp64 state, exact spike counting.
// H: [e][nblk][m][32], m = t_local*BATCH + b.
// ---------------------------------------------------------------------------
template<int S>
__global__ __launch_bounds__(256) void lif_scan_half(
    const double* __restrict__ H, const float* __restrict__ g,
    double* __restrict__ Vst, char* __restrict__ C,
    float* __restrict__ Mean, int half)
{
    const int idx = blockIdx.x * 256 + threadIdx.x;   // b*S + o
    const int b = idx / S;
    const int o = idx % S;
    const size_t ns = (size_t)(o >> 5) * M_HALF * 32 + (o & 31);

    double v[NEXP], gv[NEXP];
    #pragma unroll
    for (int e = 0; e < NEXP; ++e) {
        gv[e] = (double)g[e];
        v[e] = (half == 0) ? 0.0 : Vst[(size_t)e * BATCH * S + idx];
    }
    double acc = 0.0;
    for (int t = 0; t < 8; ++t) {
        int cnt = 0;
        double gs = 0.0;
        #pragma unroll
        for (int e = 0; e < NEXP; ++e) {
            double h = H[(size_t)e * (S / 32) * M_HALF * 32 + ns
                         + (size_t)(t * BATCH + b) * 32];
            double vv = v[e] * 0.95 + h;
            if (vv >= 1.0) { vv -= 1.0; cnt++; gs += gv[e]; }
            v[e] = vv;
        }
        C[(size_t)(half * 8 + t) * BATCH * S + idx] = (char)cnt;
        acc += gs;
    }
    #pragma unroll
    for (int e = 0; e < NEXP; ++e) Vst[(size_t)e * BATCH * S + idx] = v[e];
    if (half == 0) Mean[idx] = (float)acc;
    else           Mean[idx] = (Mean[idx] + (float)acc) * 0.0625f;
}

// ---------------------------------------------------------------------------
// ws layout (bytes):
//   h     @ 0          : 64 MB
//   vst   @ 67108864   :  8 MB
//   c1    @ 75497472   :  2 MB
//   c2    @ 77594624   :  2 MB
//   Abits @ 79691776   :  3 MB   (8192 x 48 u64)
//   B1f   @ 82837504   : 24 MB   (fragment tiles)
//   B2d   @ 108003328  :  2 MB
//   B3d   @ 110100480  :  1 MB
// total ~111 MB
// ---------------------------------------------------------------------------
extern "C" void kernel_launch(void* const* d_in, const int* in_sizes, int n_in,
                              void* d_out, int out_size, void* d_ws, size_t ws_size,
                              hipStream_t stream) {
    const float* x  = (const float*)d_in[0];
    const float* W1 = (const float*)d_in[1];
    const float* W2 = (const float*)d_in[2];
    const float* W3 = (const float*)d_in[3];
    const float* g1 = (const float*)d_in[4];
    const float* g2 = (const float*)d_in[5];
    const float* g3 = (const float*)d_in[6];
    float* out = (float*)d_out;

    char* ws = (char*)d_ws;
    double* h    = (double*)ws;
    double* vst  = (double*)(ws + 67108864ull);
    char* c1     = ws + 75497472ull;
    char* c2     = ws + 77594624ull;
    u64*  Abits  = (u64*)(ws + 79691776ull);
    char* B1f    = ws + 82837504ull;
    char* B2d    = ws + 108003328ull;
    char* B3d    = ws + 110100480ull;

    dim3 blk(256);

    // --- precompute ---
    pack_x_bits<<<(M_ROWS * N_IN) / 256, blk, 0, stream>>>(x, Abits);
    digitize_w_frag<<<(NEXP * S1 * N_IN) / 256, blk, 0, stream>>>(W1, B1f);
    digitize_w<<<((NEXP * S2 * S1 / 4) + 255) / 256, blk, 0, stream>>>(
        W2, B2d, S1, (long long)NEXP * S2 * S1 / 4);
    digitize_w<<<((NEXP * S3 * S2 / 4) + 255) / 256, blk, 0, stream>>>(
        W3, B3d, S2, (long long)NEXP * S3 * S2 / 4);

    // --- stage 1: barrier-free pipelined GEMM + LIF, two T-halves ---
    for (int half = 0; half < 2; ++half) {
        gemm_s1<<<1024, blk, 0, stream>>>(
            Abits + (size_t)half * M_HALF * (N_IN / 64), B1f, h);
        lif_scan_half<S1><<<(BATCH * S1) / 256, blk, 0, stream>>>(
            h, g1, vst, c1, out, half);
    }
    // --- stage 2 ---
    for (int half = 0; half < 2; ++half) {
        gemm_i8<S1, S2, 35><<<dim3(M_HALF / 128, NEXP * 4 * S2 / 128), blk, 0, stream>>>(
            c1 + (size_t)half * M_HALF * S1, B2d, h);
        lif_scan_half<S2><<<(BATCH * S2) / 256, blk, 0, stream>>>(
            h, g2, vst, c2, out + BATCH * S1, half);
    }
    // --- stage 3 ---
    for (int half = 0; half < 2; ++half) {
        gemm_i8<S2, S3, 35><<<dim3(M_HALF / 128, NEXP * 4 * S3 / 128), blk, 0, stream>>>(
            c2 + (size_t)half * M_HALF * S2, B3d, h);
        lif_scan_half<S3><<<(BATCH * S3) / 256, blk, 0, stream>>>(
            h, g3, vst, c1, out + BATCH * (S1 + S2), half);
    }
}

// Round 6
// 643.348 us; speedup vs baseline: 1.0041x; 1.0041x over previous
//
#include <hip/hip_runtime.h>
#include <hip/hip_bf16.h>
#include <cmath>

#define T_STEPS 16
#define BATCH   512
#define N_IN    3072
#define S1      256
#define S2      256
#define S3      128
#define NEXP    8
#define M_ROWS  (T_STEPS * BATCH)   // 8192
#define M_HALF  (M_ROWS / 2)        // 4096
#define NT1     256                 // stage-1 B fragment tiles in n (8192/32)

typedef int v4i  __attribute__((ext_vector_type(4)));
typedef int v16i __attribute__((ext_vector_type(16)));
typedef unsigned long long u64;
typedef unsigned int uint32;

// ---------------------------------------------------------------------------
// async global->LDS 16B (stages 2/3 path)
// ---------------------------------------------------------------------------
__device__ __forceinline__ void gl2lds16(const char* g, char* l) {
    __builtin_amdgcn_global_load_lds(
        (const __attribute__((address_space(1))) void*)g,
        (__attribute__((address_space(3))) void*)l, 16, 0, 0);
}

// ---------------------------------------------------------------------------
// pack binary fp32 x -> 1 bit/elem via wave ballot. bits[m][K/64] (u64).
// ---------------------------------------------------------------------------
__global__ __launch_bounds__(256) void pack_x_bits(
    const float* __restrict__ x, u64* __restrict__ bits)
{
    int gid = blockIdx.x * 256 + threadIdx.x;
    float v = x[gid];
    u64 m = __ballot(v >= 0.5f);
    if ((threadIdx.x & 63) == 0) bits[gid >> 6] = m;
}

// ---------------------------------------------------------------------------
// Stage-1 weight digitize -> MFMA fragment tiles, COALESCED.
// One thread per 16-byte output chunk: Bf[kb][nt][lane16][16],
// lane16 = (gr&31) + 32*qd, gr = nt*32 + (lane16&31) = B-row = (e*S1+n)*4+limb,
// k = kb*32 + qd*16 + kk.  Writes are lane-contiguous 16B (fully coalesced).
// NOTE: total chunks = NEXP*S1*N_IN/4 (4 limbs per weight, 16 weights/chunk).
// R5 bug was launching 1/4 of these.
// ---------------------------------------------------------------------------
__global__ __launch_bounds__(256) void digitize_w_frag(
    const float* __restrict__ W, char* __restrict__ Bf)
{
    int t = blockIdx.x * 256 + threadIdx.x;   // 96*256*64 = 1,572,864 chunks
    int lane16 = t & 63;
    int nt  = (t >> 6) & 255;
    int kb  = t >> 14;                        // 0..95
    int r   = lane16 & 31;
    int qd  = lane16 >> 5;
    int gr  = nt * 32 + r;
    int row = gr >> 2;                        // e*S1 + n
    int limb = gr & 3;
    int k0  = kb * 32 + qd * 16;

    const float4* Wp = (const float4*)(W + (size_t)row * N_IN + k0);
    char out[16];
    #pragma unroll
    for (int f4 = 0; f4 < 4; ++f4) {
        float4 w = Wp[f4];
        float ws[4] = {w.x, w.y, w.z, w.w};
        #pragma unroll
        for (int c = 0; c < 4; ++c) {
            long long q = llrint((double)ws[c] * 4294967296.0);
            int d = 0;
            #pragma unroll
            for (int l = 0; l < 4; ++l) {
                int dl = (int)((q + 128) & 255) - 128;
                q = (q - dl) >> 8;
                if (l == limb) d = dl;
            }
            out[f4 * 4 + c] = (char)d;
        }
    }
    *(v4i*)(Bf + (size_t)t * 16) = *(v4i*)out;
}

// ---------------------------------------------------------------------------
// Row-major digitize for stages 2/3 (gemm_i8 path).
// ---------------------------------------------------------------------------
__global__ __launch_bounds__(256) void digitize_w(
    const float* __restrict__ W, char* __restrict__ Bd, int K, long long total4)
{
    long long t = (long long)blockIdx.x * 256 + threadIdx.x;
    if (t >= total4) return;
    const int kq = K >> 2;
    long long row = t / kq;
    int kc = (int)(t - row * kq);
    float4 w = ((const float4*)W)[t];
    long long q[4];
    q[0] = llrint((double)w.x * 4294967296.0);
    q[1] = llrint((double)w.y * 4294967296.0);
    q[2] = llrint((double)w.z * 4294967296.0);
    q[3] = llrint((double)w.w * 4294967296.0);
    char* base = Bd + row * 4 * (long long)K + kc * 4;
    #pragma unroll
    for (int l = 0; l < 4; ++l) {
        char4 d;
        int d0 = (int)((q[0] + 128) & 255) - 128; q[0] = (q[0] - d0) >> 8;
        int d1 = (int)((q[1] + 128) & 255) - 128; q[1] = (q[1] - d1) >> 8;
        int d2 = (int)((q[2] + 128) & 255) - 128; q[2] = (q[2] - d2) >> 8;
        int d3 = (int)((q[3] + 128) & 255) - 128; q[3] = (q[3] - d3) >> 8;
        d.x = (char)d0; d.y = (char)d1; d.z = (char)d2; d.w = (char)d3;
        *(char4*)(base + (long long)l * K) = d;
    }
}

// ---------------------------------------------------------------------------
// Stage-1 GEMM v2: NO LDS, NO barriers. A-fragments built in registers from
// the bit-packed A. B fragments global->VGPR (tile layout), prefetched 1 iter;
// A bits prefetched 2 iters. Block 256 = 4 waves stacked in m; wave tile
// 64(m) x 128(B-rows): 2x4 of mfma_i32_32x32x32_i8. Grid 1-D 1024,
// id%8 = XCD -> B L2-resident. H layout: [e][nblk=8][m][32] fp64.
// ---------------------------------------------------------------------------
__global__ __launch_bounds__(256, 2) void gemm_s1(
    const u64* __restrict__ Abits, const char* __restrict__ Bf,
    double* __restrict__ H)
{
    constexpr int KI = N_IN / 64;            // 48 iters

    const int tid  = threadIdx.x;
    const int lane = tid & 63;
    const int w    = tid >> 6;
    const int col  = lane & 31;
    const int qd   = lane >> 5;
    const int sh16 = qd * 16;

    const int id    = blockIdx.x;
    const int m_blk = (id >> 3) & 15;
    const int n_blk = (id & 7) + 8 * (id >> 7);

    const int m0  = m_blk * 256 + w * 64;
    const int nb0 = n_blk * 4;

    const u64* Ab0 = Abits + (size_t)(m0 + col) * KI;
    const u64* Ab1 = Abits + (size_t)(m0 + 32 + col) * KI;

    v16i acc[2][4];
    #pragma unroll
    for (int i = 0; i < 2; ++i)
        #pragma unroll
        for (int j = 0; j < 4; ++j)
            #pragma unroll
            for (int r = 0; r < 16; ++r) acc[i][j][r] = 0;

    auto loadB = [&](int kb, int nt) -> v4i {
        return *(const v4i*)(Bf + (((size_t)kb * NT1 + nt) * 64 + lane) * 16);
    };
    // expand 16 bits (window qd*16 of dword) -> 16 i8 {0,1} bytes in v4i
    auto unpack16 = [&](uint32 dw) -> v4i {
        uint32 w16 = dw >> sh16;
        v4i d;
        #pragma unroll
        for (int c = 0; c < 4; ++c)
            d[c] = (int)((((w16 >> (4 * c)) & 0xFu) * 0x00204081u) & 0x01010101u);
        return d;
    };

    // prologue: bits for it=0,1 ; B for it=0
    u64 b0_c = Ab0[0], b1_c = Ab1[0];
    u64 b0_n = Ab0[1], b1_n = Ab1[1];
    v4i bc[8];
    #pragma unroll
    for (int ks = 0; ks < 2; ++ks)
        #pragma unroll
        for (int j = 0; j < 4; ++j) bc[ks * 4 + j] = loadB(ks, nb0 + j);

    for (int it = 0; it < KI; ++it) {
        const int itn  = (it + 1 < KI) ? it + 1 : KI - 1;
        const int itn2 = (it + 2 < KI) ? it + 2 : KI - 1;

        // prefetch B(it+1), bits(it+2)
        v4i bn[8];
        #pragma unroll
        for (int ks = 0; ks < 2; ++ks)
            #pragma unroll
            for (int j = 0; j < 4; ++j)
                bn[ks * 4 + j] = loadB(itn * 2 + ks, nb0 + j);
        u64 b0_f = Ab0[itn2];
        u64 b1_f = Ab1[itn2];

        // compute iter it, fragments straight from registers
        #pragma unroll
        for (int ks = 0; ks < 2; ++ks) {
            uint32 dw0 = (uint32)(ks ? (b0_c >> 32) : b0_c);
            uint32 dw1 = (uint32)(ks ? (b1_c >> 32) : b1_c);
            v4i af0 = unpack16(dw0);
            v4i af1 = unpack16(dw1);
            #pragma unroll
            for (int j = 0; j < 4; ++j) {
                acc[0][j] = __builtin_amdgcn_mfma_i32_32x32x32_i8(
                    af0, bc[ks * 4 + j], acc[0][j], 0, 0, 0);
                acc[1][j] = __builtin_amdgcn_mfma_i32_32x32x32_i8(
                    af1, bc[ks * 4 + j], acc[1][j], 0, 0, 0);
            }
        }
        b0_c = b0_n; b0_n = b0_f;
        b1_c = b1_n; b1_n = b1_f;
        #pragma unroll
        for (int q2 = 0; q2 < 8; ++q2) bc[q2] = bn[q2];
    }

    // epilogue: recombine 4 limbs (adjacent C cols) exactly in double
    const double sbase = 1.0 / 4294967296.0;   // 2^-32
    #pragma unroll
    for (int j = 0; j < 4; ++j) {
        int brow  = n_blk * 128 + j * 32 + col;
        int limb  = brow & 3;
        int nglob = brow >> 2;                 // e*256 + nloc
        int e     = nglob >> 8;
        int nloc  = nglob & 255;
        double lscale = (double)(1 << (8 * limb)) * sbase;
        size_t hb = (((size_t)e * 8 + (nloc >> 5)) * M_HALF) * 32 + (nloc & 31);
        #pragma unroll
        for (int i = 0; i < 2; ++i) {
            #pragma unroll
            for (int reg = 0; reg < 16; ++reg) {
                double d = (double)acc[i][j][reg] * lscale;
                d += __shfl_xor(d, 1);
                d += __shfl_xor(d, 2);
                if ((lane & 3) == 0) {
                    int m = m0 + i * 32 + (reg & 3) + 8 * (reg >> 2) + 4 * qd;
                    H[hb + (size_t)m * 32] = d;
                }
            }
        }
    }
}

// ---------------------------------------------------------------------------
// Stages 2/3 GEMM (proven R3 path).
// ---------------------------------------------------------------------------
template<int K, int S, int SHIFT>
__global__ __launch_bounds__(256) void gemm_i8(
    const char* __restrict__ A, const char* __restrict__ B,
    double* __restrict__ H)
{
    __shared__ __align__(16) char As[128 * 128];
    __shared__ __align__(16) char Bs[128 * 128];

    const int tid  = threadIdx.x;
    const int lane = tid & 63;
    const int wave = tid >> 6;
    const int wm  = (wave & 1) * 64;
    const int wn  = (wave >> 1) * 64;
    const int col = lane & 31;
    const int qd  = lane >> 5;

    const char* Ag = A + (size_t)(blockIdx.x * 128) * K;
    const char* Bg = B + (size_t)(blockIdx.y * 128) * K;

    v16i acc[2][2];
    #pragma unroll
    for (int i = 0; i < 2; ++i)
        #pragma unroll
        for (int j = 0; j < 2; ++j)
            #pragma unroll
            for (int r = 0; r < 16; ++r) acc[i][j][r] = 0;

    for (int k0 = 0; k0 < K; k0 += 128) {
        #pragma unroll
        for (int i = 0; i < 4; ++i) {
            int slot = tid + i * 256;
            int row  = slot >> 3;
            int ch   = (slot & 7) ^ (row & 7);
            gl2lds16(Ag + (size_t)row * K + k0 + ch * 16, As + slot * 16);
            gl2lds16(Bg + (size_t)row * K + k0 + ch * 16, Bs + slot * 16);
        }
        __syncthreads();

        #pragma unroll
        for (int ks = 0; ks < 4; ++ks) {
            v4i af[2], bf[2];
            #pragma unroll
            for (int i = 0; i < 2; ++i) {
                int row = wm + i * 32 + col;
                int ch  = (ks * 2 + qd) ^ (row & 7);
                af[i] = *(const v4i*)(As + row * 128 + ch * 16);
            }
            #pragma unroll
            for (int j = 0; j < 2; ++j) {
                int row = wn + j * 32 + col;
                int ch  = (ks * 2 + qd) ^ (row & 7);
                bf[j] = *(const v4i*)(Bs + row * 128 + ch * 16);
            }
            #pragma unroll
            for (int i = 0; i < 2; ++i)
                #pragma unroll
                for (int j = 0; j < 2; ++j)
                    acc[i][j] = __builtin_amdgcn_mfma_i32_32x32x32_i8(
                        af[i], bf[j], acc[i][j], 0, 0, 0);
        }
        __syncthreads();
    }

    const double sbase = 1.0 / (double)(1ll << SHIFT);
    #pragma unroll
    for (int j = 0; j < 2; ++j) {
        int brow  = blockIdx.y * 128 + wn + j * 32 + col;
        int limb  = brow & 3;
        int nglob = brow >> 2;
        int e     = nglob / S;
        int nloc  = nglob % S;
        double lscale = (double)(1 << (8 * limb)) * sbase;
        size_t hb = (((size_t)e * (S / 32) + (nloc >> 5)) * M_HALF) * 32 + (nloc & 31);
        #pragma unroll
        for (int i = 0; i < 2; ++i) {
            #pragma unroll
            for (int reg = 0; reg < 16; ++reg) {
                double d = (double)acc[i][j][reg] * lscale;
                d += __shfl_xor(d, 1);
                d += __shfl_xor(d, 2);
                if ((lane & 3) == 0) {
                    int m = blockIdx.x * 128 + wm + i * 32
                          + (reg & 3) + 8 * (reg >> 2) + 4 * qd;
                    H[hb + (size_t)m * 32] = d;
                }
            }
        }
    }
}

// ---------------------------------------------------------------------------
// LIF scan over one T-half (8 steps). fp64 state, exact spike counting.
// ---------------------------------------------------------------------------
template<int S>
__global__ __launch_bounds__(256) void lif_scan_half(
    const double* __restrict__ H, const float* __restrict__ g,
    double* __restrict__ Vst, char* __restrict__ C,
    float* __restrict__ Mean, int half)
{
    const int idx = blockIdx.x * 256 + threadIdx.x;   // b*S + o
    const int b = idx / S;
    const int o = idx % S;
    const size_t ns = (size_t)(o >> 5) * M_HALF * 32 + (o & 31);

    double v[NEXP], gv[NEXP];
    #pragma unroll
    for (int e = 0; e < NEXP; ++e) {
        gv[e] = (double)g[e];
        v[e] = (half == 0) ? 0.0 : Vst[(size_t)e * BATCH * S + idx];
    }
    double acc = 0.0;
    for (int t = 0; t < 8; ++t) {
        int cnt = 0;
        double gs = 0.0;
        #pragma unroll
        for (int e = 0; e < NEXP; ++e) {
            double h = H[(size_t)e * (S / 32) * M_HALF * 32 + ns
                         + (size_t)(t * BATCH + b) * 32];
            double vv = v[e] * 0.95 + h;
            if (vv >= 1.0) { vv -= 1.0; cnt++; gs += gv[e]; }
            v[e] = vv;
        }
        C[(size_t)(half * 8 + t) * BATCH * S + idx] = (char)cnt;
        acc += gs;
    }
    #pragma unroll
    for (int e = 0; e < NEXP; ++e) Vst[(size_t)e * BATCH * S + idx] = v[e];
    if (half == 0) Mean[idx] = (float)acc;
    else           Mean[idx] = (Mean[idx] + (float)acc) * 0.0625f;
}

// ---------------------------------------------------------------------------
// ws layout (bytes):
//   h     @ 0          : 64 MB
//   vst   @ 67108864   :  8 MB
//   c1    @ 75497472   :  2 MB
//   c2    @ 77594624   :  2 MB
//   Abits @ 79691776   :  3 MB
//   B1f   @ 82837504   : 24 MB
//   B2d   @ 108003328  :  2 MB
//   B3d   @ 110100480  :  1 MB
// ---------------------------------------------------------------------------
extern "C" void kernel_launch(void* const* d_in, const int* in_sizes, int n_in,
                              void* d_out, int out_size, void* d_ws, size_t ws_size,
                              hipStream_t stream) {
    const float* x  = (const float*)d_in[0];
    const float* W1 = (const float*)d_in[1];
    const float* W2 = (const float*)d_in[2];
    const float* W3 = (const float*)d_in[3];
    const float* g1 = (const float*)d_in[4];
    const float* g2 = (const float*)d_in[5];
    const float* g3 = (const float*)d_in[6];
    float* out = (float*)d_out;

    char* ws = (char*)d_ws;
    double* h    = (double*)ws;
    double* vst  = (double*)(ws + 67108864ull);
    char* c1     = ws + 75497472ull;
    char* c2     = ws + 77594624ull;
    u64*  Abits  = (u64*)(ws + 79691776ull);
    char* B1f    = ws + 82837504ull;
    char* B2d    = ws + 108003328ull;
    char* B3d    = ws + 110100480ull;

    dim3 blk(256);

    // --- precompute ---
    pack_x_bits<<<(M_ROWS * N_IN) / 256, blk, 0, stream>>>(x, Abits);
    // chunks = weights * 4 limbs / 16 B = NEXP*S1*N_IN/4   (R5 bug: /16)
    digitize_w_frag<<<(NEXP * S1 * N_IN / 4) / 256, blk, 0, stream>>>(W1, B1f);
    digitize_w<<<((NEXP * S2 * S1 / 4) + 255) / 256, blk, 0, stream>>>(
        W2, B2d, S1, (long long)NEXP * S2 * S1 / 4);
    digitize_w<<<((NEXP * S3 * S2 / 4) + 255) / 256, blk, 0, stream>>>(
        W3, B3d, S2, (long long)NEXP * S3 * S2 / 4);

    // --- stage 1: register-pipelined barrier-free GEMM + LIF, two halves ---
    for (int half = 0; half < 2; ++half) {
        gemm_s1<<<1024, blk, 0, stream>>>(
            Abits + (size_t)half * M_HALF * (N_IN / 64), B1f, h);
        lif_scan_half<S1><<<(BATCH * S1) / 256, blk, 0, stream>>>(
            h, g1, vst, c1, out, half);
    }
    // --- stage 2 ---
    for (int half = 0; half < 2; ++half) {
        gemm_i8<S1, S2, 35><<<dim3(M_HALF / 128, NEXP * 4 * S2 / 128), blk, 0, stream>>>(
            c1 + (size_t)half * M_HALF * S1, B2d, h);
        lif_scan_half<S2><<<(BATCH * S2) / 256, blk, 0, stream>>>(
            h, g2, vst, c2, out + BATCH * S1, half);
    }
    // --- stage 3 ---
    for (int half = 0; half < 2; ++half) {
        gemm_i8<S2, S3, 35><<<dim3(M_HALF / 128, NEXP * 4 * S3 / 128), blk, 0, stream>>>(
            c2 + (size_t)half * M_HALF * S2, B3d, h);
        lif_scan_half<S3><<<(BATCH * S3) / 256, blk, 0, stream>>>(
            h, g3, vst, c1, out + BATCH * (S1 + S2), half);
    }
}

// Round 7
// 629.087 us; speedup vs baseline: 1.0269x; 1.0227x over previous
//
#include <hip/hip_runtime.h>
#include <hip/hip_bf16.h>
#include <cmath>

#define T_STEPS 16
#define BATCH   512
#define N_IN    3072
#define S1      256
#define S2      256
#define S3      128
#define NEXP    8
#define M_ROWS  (T_STEPS * BATCH)   // 8192

typedef int v4i  __attribute__((ext_vector_type(4)));
typedef int v16i __attribute__((ext_vector_type(16)));
typedef unsigned long long u64;
typedef unsigned int uint32;

// ---------------------------------------------------------------------------
// pack binary fp32 x -> 1 bit/elem. Output row m' = b*16 + t (t-major inner),
// 48 u64 words per row. Wave handles 64 consecutive k of one (t,b).
// ---------------------------------------------------------------------------
__global__ __launch_bounds__(256) void pack_x_bits(
    const float* __restrict__ x, u64* __restrict__ bits)
{
    int gid = blockIdx.x * 256 + threadIdx.x;
    float v = x[gid];
    u64 m = __ballot(v >= 0.5f);
    if ((threadIdx.x & 63) == 0) {
        int tb = gid / N_IN;                 // t*512 + b
        int k  = gid - tb * N_IN;
        int t  = tb >> 9;
        int b  = tb & 511;
        bits[(size_t)(b * 16 + t) * (N_IN / 64) + (k >> 6)] = m;
    }
}

// ---------------------------------------------------------------------------
// Weight digitize -> MFMA fragment tiles. B-row gr = o*32 + e*4 + limb
// (all experts/limbs of one output adjacent). Bf[kb][nt=o][lane16][16],
// lane16 = (e*4+limb) + 32*qd, k = kb*32 + qd*16 + byte.
// One thread per 16-byte chunk (coalesced stores). w -> round(w*2^32) digits.
// ---------------------------------------------------------------------------
template<int S, int K>
__global__ __launch_bounds__(256) void digitize_w_frag(
    const float* __restrict__ W, char* __restrict__ Bf)
{
    constexpr int LOGS = (S == 256) ? 8 : 7;
    int t = blockIdx.x * 256 + threadIdx.x;   // chunks = 2*S*K
    int lane16 = t & 63;
    int o  = (t >> 6) & (S - 1);
    int kb = t >> (6 + LOGS);
    int r  = lane16 & 31;
    int qd = lane16 >> 5;
    int e    = r >> 2;
    int limb = r & 3;
    int k0 = kb * 32 + qd * 16;

    const float4* Wp = (const float4*)(W + ((size_t)e * S + o) * K + k0);
    char out[16];
    #pragma unroll
    for (int f4 = 0; f4 < 4; ++f4) {
        float4 w = Wp[f4];
        float ws[4] = {w.x, w.y, w.z, w.w};
        #pragma unroll
        for (int c = 0; c < 4; ++c) {
            long long q = llrint((double)ws[c] * 4294967296.0);
            int d = 0;
            #pragma unroll
            for (int l = 0; l < 4; ++l) {
                int dl = (int)((q + 128) & 255) - 128;
                q = (q - dl) >> 8;
                if (l == limb) d = dl;
            }
            out[f4 * 4 + c] = (char)d;
        }
    }
    *(v4i*)(Bf + (size_t)t * 16) = *(v4i*)out;
}

// ---------------------------------------------------------------------------
// Fused expert-GEMM + limb recombine + LIF scan + gated combine + mean.
// Block 128(m') x 128(B-rows), 4 waves in 2x2, wave tile 64x64
// (2x2 v16i acc = 64 AGPRs -> 3 waves/SIMD with launch_bounds(256,3)).
// m' = b*16 + t  ->  one block covers 8 b x 16 t x 4 o x 8 e x 4 limb:
// everything needed for the full-T LIF scan of its (b,o) patch.
// A: ABITS ? bit-packed (reg unpack) : i8 counts (direct 16B loads).
// B: fragment tiles, global->VGPR, prefetched 1 iter.
// Epilogue: shfl limb-recombine -> LDS hs[128][32] -> per-thread LIF over
// t=0..15, e-combine via 8-lane shfl, write i8 counts (stage feed) + mean.
// No h buffer, no barriers in the K-loop (one __syncthreads before LIF).
// ---------------------------------------------------------------------------
template<int K, int S, int SHIFT, bool ABITS, bool WRITEC>
__global__ __launch_bounds__(256, 3) void fused_stage(
    const void* __restrict__ Ap, const char* __restrict__ Bf,
    const float* __restrict__ g, char* __restrict__ C,
    float* __restrict__ Mean)
{
    constexpr int KI = K / 64;
    constexpr int NT = S;                    // number of 32-row n-tiles
    __shared__ double hs[128][32];

    const int tid  = threadIdx.x;
    const int lane = tid & 63;
    const int w    = tid >> 6;
    const int col  = lane & 31;
    const int qd   = lane >> 5;
    const int wm   = (w & 1) * 64;
    const int wn   = (w >> 1) * 64;

    const int mblk = blockIdx.x;
    const int nblk = blockIdx.y;
    const int m0   = mblk * 128;

    // wave's two n-tiles: nt0, nt0+1
    const int nt0 = nblk * 4 + (wn >> 5);
    const char* Bbase = Bf + ((size_t)nt0 * 64 + lane) * 16;

    v16i acc[2][2];
    #pragma unroll
    for (int i = 0; i < 2; ++i)
        #pragma unroll
        for (int j = 0; j < 2; ++j)
            #pragma unroll
            for (int r = 0; r < 16; ++r) acc[i][j][r] = 0;

    const int ar0 = m0 + wm + col;
    const int ar1 = ar0 + 32;

    auto loadB = [&](int kb, int jj) -> v4i {
        return *(const v4i*)(Bbase + (size_t)kb * (NT * 1024) + jj * 1024);
    };

    if constexpr (ABITS) {
        const u64* A0 = (const u64*)Ap + (size_t)ar0 * KI;
        const u64* A1 = (const u64*)Ap + (size_t)ar1 * KI;
        const int sh16 = qd * 16;
        auto unpack16 = [&](uint32 dw) -> v4i {
            uint32 w16 = dw >> sh16;
            v4i d;
            #pragma unroll
            for (int c = 0; c < 4; ++c)
                d[c] = (int)((((w16 >> (4 * c)) & 0xFu) * 0x00204081u) & 0x01010101u);
            return d;
        };
        u64 c0 = A0[0], c1b = A1[0];
        u64 n0 = A0[1], n1b = A1[1];
        v4i bc[4];
        #pragma unroll
        for (int ks = 0; ks < 2; ++ks)
            #pragma unroll
            for (int jj = 0; jj < 2; ++jj) bc[ks * 2 + jj] = loadB(ks, jj);

        for (int it = 0; it < KI; ++it) {
            const int itn  = (it + 1 < KI) ? it + 1 : KI - 1;
            const int itn2 = (it + 2 < KI) ? it + 2 : KI - 1;
            v4i bn[4];
            #pragma unroll
            for (int ks = 0; ks < 2; ++ks)
                #pragma unroll
                for (int jj = 0; jj < 2; ++jj)
                    bn[ks * 2 + jj] = loadB(itn * 2 + ks, jj);
            u64 f0 = A0[itn2], f1 = A1[itn2];

            #pragma unroll
            for (int ks = 0; ks < 2; ++ks) {
                uint32 dw0 = ks ? (uint32)(c0 >> 32) : (uint32)c0;
                uint32 dw1 = ks ? (uint32)(c1b >> 32) : (uint32)c1b;
                v4i af0 = unpack16(dw0);
                v4i af1 = unpack16(dw1);
                acc[0][0] = __builtin_amdgcn_mfma_i32_32x32x32_i8(af0, bc[ks*2+0], acc[0][0], 0,0,0);
                acc[0][1] = __builtin_amdgcn_mfma_i32_32x32x32_i8(af0, bc[ks*2+1], acc[0][1], 0,0,0);
                acc[1][0] = __builtin_amdgcn_mfma_i32_32x32x32_i8(af1, bc[ks*2+0], acc[1][0], 0,0,0);
                acc[1][1] = __builtin_amdgcn_mfma_i32_32x32x32_i8(af1, bc[ks*2+1], acc[1][1], 0,0,0);
            }
            c0 = n0; n0 = f0;
            c1b = n1b; n1b = f1;
            #pragma unroll
            for (int q2 = 0; q2 < 4; ++q2) bc[q2] = bn[q2];
        }
    } else {
        const char* A0 = (const char*)Ap + (size_t)ar0 * K;
        const char* A1 = (const char*)Ap + (size_t)ar1 * K;
        v4i ac[4], bc[4];
        #pragma unroll
        for (int ks = 0; ks < 2; ++ks) {
            ac[ks * 2 + 0] = *(const v4i*)(A0 + ks * 32 + qd * 16);
            ac[ks * 2 + 1] = *(const v4i*)(A1 + ks * 32 + qd * 16);
            #pragma unroll
            for (int jj = 0; jj < 2; ++jj) bc[ks * 2 + jj] = loadB(ks, jj);
        }
        for (int it = 0; it < KI; ++it) {
            const int itn = (it + 1 < KI) ? it + 1 : KI - 1;
            v4i an[4], bn[4];
            #pragma unroll
            for (int ks = 0; ks < 2; ++ks) {
                an[ks * 2 + 0] = *(const v4i*)(A0 + itn * 64 + ks * 32 + qd * 16);
                an[ks * 2 + 1] = *(const v4i*)(A1 + itn * 64 + ks * 32 + qd * 16);
                #pragma unroll
                for (int jj = 0; jj < 2; ++jj)
                    bn[ks * 2 + jj] = loadB(itn * 2 + ks, jj);
            }
            #pragma unroll
            for (int ks = 0; ks < 2; ++ks) {
                acc[0][0] = __builtin_amdgcn_mfma_i32_32x32x32_i8(ac[ks*2+0], bc[ks*2+0], acc[0][0], 0,0,0);
                acc[0][1] = __builtin_amdgcn_mfma_i32_32x32x32_i8(ac[ks*2+0], bc[ks*2+1], acc[0][1], 0,0,0);
                acc[1][0] = __builtin_amdgcn_mfma_i32_32x32x32_i8(ac[ks*2+1], bc[ks*2+0], acc[1][0], 0,0,0);
                acc[1][1] = __builtin_amdgcn_mfma_i32_32x32x32_i8(ac[ks*2+1], bc[ks*2+1], acc[1][1], 0,0,0);
            }
            #pragma unroll
            for (int q2 = 0; q2 < 4; ++q2) { ac[q2] = an[q2]; bc[q2] = bn[q2]; }
        }
    }

    // ---- limb recombine (exact, in double) -> LDS h tile ----
    const double sbase = 1.0 / (double)(1ll << SHIFT);
    const int limb = col & 3;
    const double lscale = (double)(1 << (8 * limb)) * sbase;
    #pragma unroll
    for (int j = 0; j < 2; ++j) {
        const int oe = ((wn >> 5) + j) * 8 + (col >> 2);   // o_loc*8 + e
        #pragma unroll
        for (int i = 0; i < 2; ++i) {
            #pragma unroll
            for (int reg = 0; reg < 16; ++reg) {
                double d = (double)acc[i][j][reg] * lscale;
                d += __shfl_xor(d, 1);
                d += __shfl_xor(d, 2);
                if ((col & 3) == 0) {
                    int m = wm + i * 32 + (reg & 3) + 8 * (reg >> 2) + 4 * qd;
                    hs[m][oe] = d;
                }
            }
        }
    }
    __syncthreads();

    // ---- LIF scan: thread = (b_loc = tid>>5, o_loc = (tid>>3)&3, e = tid&7)
    const int b_loc = tid >> 5;
    const int oe    = tid & 31;
    const int e     = tid & 7;
    const float ge  = g[e];
    const int bg = mblk * 8 + b_loc;
    const int og = nblk * 4 + ((tid >> 3) & 3);

    double v = 0.0;
    float gacc = 0.0f;
    #pragma unroll
    for (int t = 0; t < T_STEPS; ++t) {
        double h  = hs[b_loc * 16 + t][oe];
        double vv = v * 0.95 + h;
        int spk = (vv >= 1.0) ? 1 : 0;
        v = vv - (double)spk;
        float gs = ge * (float)spk;
        gs += __shfl_xor(gs, 1);
        gs += __shfl_xor(gs, 2);
        gs += __shfl_xor(gs, 4);
        gacc += gs;
        if (WRITEC) {
            int cnt = spk;
            cnt += __shfl_xor(cnt, 1);
            cnt += __shfl_xor(cnt, 2);
            cnt += __shfl_xor(cnt, 4);
            if (e == 0)
                C[(size_t)(bg * 16 + t) * S + og] = (char)cnt;
        }
    }
    if (e == 0) Mean[(size_t)bg * S + og] = gacc * 0.0625f;
}

// ---------------------------------------------------------------------------
// ws layout (bytes):
//   Abits @ 0          : 3 MB   (8192 x 48 u64, m' = b*16+t)
//   B1f   @ 3145728    : 24 MB
//   B2f   @ 28311552   :  2 MB
//   B3f   @ 30408704   :  1 MB
//   c1    @ 31457280   :  2 MB  (i8 counts, rows m' = b*16+t, 256 cols)
//   c2    @ 33554432   :  2 MB
// total ~34 MB (no h, no vst)
// ---------------------------------------------------------------------------
extern "C" void kernel_launch(void* const* d_in, const int* in_sizes, int n_in,
                              void* d_out, int out_size, void* d_ws, size_t ws_size,
                              hipStream_t stream) {
    const float* x  = (const float*)d_in[0];
    const float* W1 = (const float*)d_in[1];
    const float* W2 = (const float*)d_in[2];
    const float* W3 = (const float*)d_in[3];
    const float* g1 = (const float*)d_in[4];
    const float* g2 = (const float*)d_in[5];
    const float* g3 = (const float*)d_in[6];
    float* out = (float*)d_out;

    char* ws = (char*)d_ws;
    u64*  Abits = (u64*)ws;
    char* B1f   = ws + 3145728ull;
    char* B2f   = ws + 28311552ull;
    char* B3f   = ws + 30408704ull;
    char* c1    = ws + 31457280ull;
    char* c2    = ws + 33554432ull;

    dim3 blk(256);

    // --- precompute ---
    pack_x_bits<<<(M_ROWS * N_IN) / 256, blk, 0, stream>>>(x, Abits);
    digitize_w_frag<S1, N_IN><<<(2 * S1 * N_IN) / 256, blk, 0, stream>>>(W1, B1f);
    digitize_w_frag<S2, S1><<<(2 * S2 * S1) / 256, blk, 0, stream>>>(W2, B2f);
    digitize_w_frag<S3, S2><<<(2 * S3 * S2) / 256, blk, 0, stream>>>(W3, B3f);

    // --- three fused GEMM+LIF stages (full T each, no intermediate h) ---
    fused_stage<N_IN, S1, 32, true,  true ><<<dim3(64, 64), blk, 0, stream>>>(
        Abits, B1f, g1, c1, out);
    fused_stage<S1,   S2, 35, false, true ><<<dim3(64, 64), blk, 0, stream>>>(
        c1, B2f, g2, c2, out + BATCH * S1);
    fused_stage<S2,   S3, 35, false, false><<<dim3(64, 32), blk, 0, stream>>>(
        c2, B3f, g3, nullptr, out + BATCH * (S1 + S2));
}

// Round 8
// 624.423 us; speedup vs baseline: 1.0346x; 1.0075x over previous
//
#include <hip/hip_runtime.h>
#include <hip/hip_bf16.h>
#include <cmath>

#define T_STEPS 16
#define BATCH   512
#define N_IN    3072
#define S1      256
#define S2      256
#define S3      128
#define NEXP    8
#define M_ROWS  (T_STEPS * BATCH)   // 8192

typedef int v4i  __attribute__((ext_vector_type(4)));
typedef int v16i __attribute__((ext_vector_type(16)));
typedef unsigned long long u64;
typedef unsigned int uint32;

// ---------------------------------------------------------------------------
// pack binary fp32 x -> 1 bit/elem. Output row m' = b*16 + t (t-major inner),
// 48 u64 words per row.
// ---------------------------------------------------------------------------
__global__ __launch_bounds__(256) void pack_x_bits(
    const float* __restrict__ x, u64* __restrict__ bits)
{
    int gid = blockIdx.x * 256 + threadIdx.x;
    float v = x[gid];
    u64 m = __ballot(v >= 0.5f);
    if ((threadIdx.x & 63) == 0) {
        int tb = gid / N_IN;                 // t*512 + b
        int k  = gid - tb * N_IN;
        int t  = tb >> 9;
        int b  = tb & 511;
        bits[(size_t)(b * 16 + t) * (N_IN / 64) + (k >> 6)] = m;
    }
}

// ---------------------------------------------------------------------------
// Weight digitize -> MFMA fragment tiles. B-row gr = o*32 + e*4 + limb.
// Bf[kb][nt=o][lane16][16], lane16 = (e*4+limb) + 32*qd, k = kb*32+qd*16+byte.
// One thread per 16-byte chunk (coalesced stores).
// ---------------------------------------------------------------------------
template<int S, int K>
__global__ __launch_bounds__(256) void digitize_w_frag(
    const float* __restrict__ W, char* __restrict__ Bf)
{
    constexpr int LOGS = (S == 256) ? 8 : 7;
    int t = blockIdx.x * 256 + threadIdx.x;   // chunks = 2*S*K
    int lane16 = t & 63;
    int o  = (t >> 6) & (S - 1);
    int kb = t >> (6 + LOGS);
    int r  = lane16 & 31;
    int qd = lane16 >> 5;
    int e    = r >> 2;
    int limb = r & 3;
    int k0 = kb * 32 + qd * 16;

    const float4* Wp = (const float4*)(W + ((size_t)e * S + o) * K + k0);
    char out[16];
    #pragma unroll
    for (int f4 = 0; f4 < 4; ++f4) {
        float4 w = Wp[f4];
        float ws[4] = {w.x, w.y, w.z, w.w};
        #pragma unroll
        for (int c = 0; c < 4; ++c) {
            long long q = llrint((double)ws[c] * 4294967296.0);
            int d = 0;
            #pragma unroll
            for (int l = 0; l < 4; ++l) {
                int dl = (int)((q + 128) & 255) - 128;
                q = (q - dl) >> 8;
                if (l == limb) d = dl;
            }
            out[f4 * 4 + c] = (char)d;
        }
    }
    *(v4i*)(Bf + (size_t)t * 16) = *(v4i*)out;
}

// ---------------------------------------------------------------------------
// Fused expert-GEMM + limb recombine + LIF scan + gated combine + mean.
// Block 128(m') x 128(B-rows), 4 waves 2x2, wave tile 64x64.
// 1-D grid with XCD swizzle: xcd = id&7 owns n-slab [xcd*NS, (xcd+1)*NS)
// -> per-XCD B working set = B_bytes/8 (stage1: 3 MB, L2-resident).
// NBLK = number of n-blocks (grid.x = 64*NBLK), NS = NBLK/8.
// ---------------------------------------------------------------------------
template<int K, int S, int SHIFT, bool ABITS, bool WRITEC, int NBLK>
__global__ __launch_bounds__(256, 4) void fused_stage(
    const void* __restrict__ Ap, const char* __restrict__ Bf,
    const float* __restrict__ g, char* __restrict__ C,
    float* __restrict__ Mean)
{
    constexpr int KI = K / 64;
    constexpr int NT = S;                    // number of 32-row n-tiles
    constexpr int NS = NBLK / 8;
    __shared__ double hs[128][32];

    const int tid  = threadIdx.x;
    const int lane = tid & 63;
    const int w    = tid >> 6;
    const int col  = lane & 31;
    const int qd   = lane >> 5;
    const int wm   = (w & 1) * 64;
    const int wn   = (w >> 1) * 64;

    // XCD-swizzled block mapping: id = mblk*NBLK + inner*8 + xcd
    const int id   = blockIdx.x;
    const int nblk = (id & 7) * NS + ((id >> 3) % NS);
    const int mblk = id / NBLK;
    const int m0   = mblk * 128;

    // wave's two n-tiles: nt0, nt0+1
    const int nt0 = nblk * 4 + (wn >> 5);
    const char* Bbase = Bf + ((size_t)nt0 * 64 + lane) * 16;

    v16i acc[2][2];
    #pragma unroll
    for (int i = 0; i < 2; ++i)
        #pragma unroll
        for (int j = 0; j < 2; ++j)
            #pragma unroll
            for (int r = 0; r < 16; ++r) acc[i][j][r] = 0;

    const int ar0 = m0 + wm + col;
    const int ar1 = ar0 + 32;

    auto loadB = [&](int kb, int jj) -> v4i {
        return *(const v4i*)(Bbase + (size_t)kb * (NT * 1024) + jj * 1024);
    };

    if constexpr (ABITS) {
        const u64* A0 = (const u64*)Ap + (size_t)ar0 * KI;
        const u64* A1 = (const u64*)Ap + (size_t)ar1 * KI;
        const int sh16 = qd * 16;
        auto unpack16 = [&](uint32 dw) -> v4i {
            uint32 w16 = dw >> sh16;
            v4i d;
            #pragma unroll
            for (int c = 0; c < 4; ++c)
                d[c] = (int)((((w16 >> (4 * c)) & 0xFu) * 0x00204081u) & 0x01010101u);
            return d;
        };
        u64 c0 = A0[0], c1b = A1[0];
        u64 n0 = A0[1], n1b = A1[1];
        v4i bc[4];
        #pragma unroll
        for (int ks = 0; ks < 2; ++ks)
            #pragma unroll
            for (int jj = 0; jj < 2; ++jj) bc[ks * 2 + jj] = loadB(ks, jj);

        for (int it = 0; it < KI; ++it) {
            const int itn  = (it + 1 < KI) ? it + 1 : KI - 1;
            const int itn2 = (it + 2 < KI) ? it + 2 : KI - 1;
            v4i bn[4];
            #pragma unroll
            for (int ks = 0; ks < 2; ++ks)
                #pragma unroll
                for (int jj = 0; jj < 2; ++jj)
                    bn[ks * 2 + jj] = loadB(itn * 2 + ks, jj);
            u64 f0 = A0[itn2], f1 = A1[itn2];

            #pragma unroll
            for (int ks = 0; ks < 2; ++ks) {
                uint32 dw0 = ks ? (uint32)(c0 >> 32) : (uint32)c0;
                uint32 dw1 = ks ? (uint32)(c1b >> 32) : (uint32)c1b;
                v4i af0 = unpack16(dw0);
                v4i af1 = unpack16(dw1);
                acc[0][0] = __builtin_amdgcn_mfma_i32_32x32x32_i8(af0, bc[ks*2+0], acc[0][0], 0,0,0);
                acc[0][1] = __builtin_amdgcn_mfma_i32_32x32x32_i8(af0, bc[ks*2+1], acc[0][1], 0,0,0);
                acc[1][0] = __builtin_amdgcn_mfma_i32_32x32x32_i8(af1, bc[ks*2+0], acc[1][0], 0,0,0);
                acc[1][1] = __builtin_amdgcn_mfma_i32_32x32x32_i8(af1, bc[ks*2+1], acc[1][1], 0,0,0);
            }
            c0 = n0; n0 = f0;
            c1b = n1b; n1b = f1;
            #pragma unroll
            for (int q2 = 0; q2 < 4; ++q2) bc[q2] = bn[q2];
        }
    } else {
        const char* A0 = (const char*)Ap + (size_t)ar0 * K;
        const char* A1 = (const char*)Ap + (size_t)ar1 * K;
        v4i ac[4], bc[4];
        #pragma unroll
        for (int ks = 0; ks < 2; ++ks) {
            ac[ks * 2 + 0] = *(const v4i*)(A0 + ks * 32 + qd * 16);
            ac[ks * 2 + 1] = *(const v4i*)(A1 + ks * 32 + qd * 16);
            #pragma unroll
            for (int jj = 0; jj < 2; ++jj) bc[ks * 2 + jj] = loadB(ks, jj);
        }
        for (int it = 0; it < KI; ++it) {
            const int itn = (it + 1 < KI) ? it + 1 : KI - 1;
            v4i an[4], bn[4];
            #pragma unroll
            for (int ks = 0; ks < 2; ++ks) {
                an[ks * 2 + 0] = *(const v4i*)(A0 + itn * 64 + ks * 32 + qd * 16);
                an[ks * 2 + 1] = *(const v4i*)(A1 + itn * 64 + ks * 32 + qd * 16);
                #pragma unroll
                for (int jj = 0; jj < 2; ++jj)
                    bn[ks * 2 + jj] = loadB(itn * 2 + ks, jj);
            }
            #pragma unroll
            for (int ks = 0; ks < 2; ++ks) {
                acc[0][0] = __builtin_amdgcn_mfma_i32_32x32x32_i8(ac[ks*2+0], bc[ks*2+0], acc[0][0], 0,0,0);
                acc[0][1] = __builtin_amdgcn_mfma_i32_32x32x32_i8(ac[ks*2+0], bc[ks*2+1], acc[0][1], 0,0,0);
                acc[1][0] = __builtin_amdgcn_mfma_i32_32x32x32_i8(ac[ks*2+1], bc[ks*2+0], acc[1][0], 0,0,0);
                acc[1][1] = __builtin_amdgcn_mfma_i32_32x32x32_i8(ac[ks*2+1], bc[ks*2+1], acc[1][1], 0,0,0);
            }
            #pragma unroll
            for (int q2 = 0; q2 < 4; ++q2) { ac[q2] = an[q2]; bc[q2] = bn[q2]; }
        }
    }

    // ---- limb recombine (exact, in double) -> LDS h tile ----
    const double sbase = 1.0 / (double)(1ll << SHIFT);
    const int limb = col & 3;
    const double lscale = (double)(1 << (8 * limb)) * sbase;
    #pragma unroll
    for (int j = 0; j < 2; ++j) {
        const int oe = ((wn >> 5) + j) * 8 + (col >> 2);   // o_loc*8 + e
        #pragma unroll
        for (int i = 0; i < 2; ++i) {
            #pragma unroll
            for (int reg = 0; reg < 16; ++reg) {
                double d = (double)acc[i][j][reg] * lscale;
                d += __shfl_xor(d, 1);
                d += __shfl_xor(d, 2);
                if ((col & 3) == 0) {
                    int m = wm + i * 32 + (reg & 3) + 8 * (reg >> 2) + 4 * qd;
                    hs[m][oe] = d;
                }
            }
        }
    }
    __syncthreads();

    // ---- LIF scan: thread = (b_loc = tid>>5, o_loc = (tid>>3)&3, e = tid&7)
    const int b_loc = tid >> 5;
    const int oe    = tid & 31;
    const int e     = tid & 7;
    const float ge  = g[e];
    const int bg = mblk * 8 + b_loc;
    const int og = nblk * 4 + ((tid >> 3) & 3);

    double v = 0.0;
    float gacc = 0.0f;
    #pragma unroll
    for (int t = 0; t < T_STEPS; ++t) {
        double h  = hs[b_loc * 16 + t][oe];
        double vv = v * 0.95 + h;
        int spk = (vv >= 1.0) ? 1 : 0;
        v = vv - (double)spk;
        float gs = ge * (float)spk;
        gs += __shfl_xor(gs, 1);
        gs += __shfl_xor(gs, 2);
        gs += __shfl_xor(gs, 4);
        gacc += gs;
        if (WRITEC) {
            int cnt = spk;
            cnt += __shfl_xor(cnt, 1);
            cnt += __shfl_xor(cnt, 2);
            cnt += __shfl_xor(cnt, 4);
            if (e == 0)
                C[(size_t)(bg * 16 + t) * S + og] = (char)cnt;
        }
    }
    if (e == 0) Mean[(size_t)bg * S + og] = gacc * 0.0625f;
}

// ---------------------------------------------------------------------------
// ws layout (bytes):
//   Abits @ 0          : 3 MB   (8192 x 48 u64, m' = b*16+t)
//   B1f   @ 3145728    : 24 MB
//   B2f   @ 28311552   :  2 MB
//   B3f   @ 30408704   :  1 MB
//   c1    @ 31457280   :  2 MB  (i8 counts, rows m' = b*16+t, 256 cols)
//   c2    @ 33554432   :  2 MB
// ---------------------------------------------------------------------------
extern "C" void kernel_launch(void* const* d_in, const int* in_sizes, int n_in,
                              void* d_out, int out_size, void* d_ws, size_t ws_size,
                              hipStream_t stream) {
    const float* x  = (const float*)d_in[0];
    const float* W1 = (const float*)d_in[1];
    const float* W2 = (const float*)d_in[2];
    const float* W3 = (const float*)d_in[3];
    const float* g1 = (const float*)d_in[4];
    const float* g2 = (const float*)d_in[5];
    const float* g3 = (const float*)d_in[6];
    float* out = (float*)d_out;

    char* ws = (char*)d_ws;
    u64*  Abits = (u64*)ws;
    char* B1f   = ws + 3145728ull;
    char* B2f   = ws + 28311552ull;
    char* B3f   = ws + 30408704ull;
    char* c1    = ws + 31457280ull;
    char* c2    = ws + 33554432ull;

    dim3 blk(256);

    // --- precompute ---
    pack_x_bits<<<(M_ROWS * N_IN) / 256, blk, 0, stream>>>(x, Abits);
    digitize_w_frag<S1, N_IN><<<(2 * S1 * N_IN) / 256, blk, 0, stream>>>(W1, B1f);
    digitize_w_frag<S2, S1><<<(2 * S2 * S1) / 256, blk, 0, stream>>>(W2, B2f);
    digitize_w_frag<S3, S2><<<(2 * S3 * S2) / 256, blk, 0, stream>>>(W3, B3f);

    // --- three fused GEMM+LIF stages, XCD-swizzled 1-D grids ---
    fused_stage<N_IN, S1, 32, true,  true,  64><<<64 * 64, blk, 0, stream>>>(
        Abits, B1f, g1, c1, out);
    fused_stage<S1,   S2, 35, false, true,  64><<<64 * 64, blk, 0, stream>>>(
        c1, B2f, g2, c2, out + BATCH * S1);
    fused_stage<S2,   S3, 35, false, false, 32><<<64 * 32, blk, 0, stream>>>(
        c2, B3f, g3, nullptr, out + BATCH * (S1 + S2));
}